// Round 6
// baseline (338.767 us; speedup 1.0000x reference)
//
#include <hip/hip_runtime.h>
#include <hip/hip_cooperative_groups.h>
#include <stdint.h>

namespace cg = cooperative_groups;

// SpMM: COO sparse A (16384x16384, 1,048,576 nnz) @ dense B (16384x256) -> out (16384x256)
// CSR-build + wave-per-row SpMM.
//
// Round-6: the 4 setup dispatches (memset/hist/scan/scatter, ~134us wall but
// ~25-30us of modeled work) are fused into ONE cooperative kernel with
// grid.sync() between phases. Removes 3+ inter-dispatch drains and makes the
// build cost visible as a single dispatch in the profile. spmm is unchanged
// (control; sits at ~3.5TB/s beyond-L2 fetch on 404MB).

#define M_ROWS 16384
#define NNZ_C  1048576
#define NCOL   256

// ---------------- fused CSR build: zero + hist + scan + scatter ----------------
__global__ __launch_bounds__(1024) void build_csr_kernel(
    const int* __restrict__ idx,        // [2, NNZ] int32: rows then cols
    const float* __restrict__ vals,
    unsigned int* __restrict__ counts,  // 16384 u32; becomes cursor after scan
    unsigned int* __restrict__ offsets, // 16385 u32
    int2* __restrict__ pairs)           // NNZ (col, val_bits)
{
    cg::grid_group grid = cg::this_grid();
    const int tid = blockIdx.x * 1024 + threadIdx.x;   // 0..262143 (= NNZ/4)

    // phase 0: zero counts (4096 uint4)
    if (tid < 4096) ((uint4*)counts)[tid] = make_uint4(0u, 0u, 0u, 0u);
    grid.sync();

    // phase 1: histogram, 4 nnz/thread (rows kept in registers for phase 3)
    const int4 r4 = ((const int4*)idx)[tid];
    atomicAdd(&counts[r4.x], 1u);
    atomicAdd(&counts[r4.y], 1u);
    atomicAdd(&counts[r4.z], 1u);
    atomicAdd(&counts[r4.w], 1u);
    grid.sync();

    // phase 2: exclusive scan of 16384 counts (block 0 only; 16 bins/thread)
    __shared__ unsigned int lds[1024];
    if (blockIdx.x == 0) {
        const int t = threadIdx.x;
        const uint4* c4 = (const uint4*)counts;
        uint4 L[4];
#pragma unroll
        for (int k = 0; k < 4; ++k) L[k] = c4[t * 4 + k];
        unsigned int local[16];
#pragma unroll
        for (int k = 0; k < 4; ++k) {
            local[k * 4 + 0] = L[k].x;
            local[k * 4 + 1] = L[k].y;
            local[k * 4 + 2] = L[k].z;
            local[k * 4 + 3] = L[k].w;
        }
        unsigned int sum = 0;
#pragma unroll
        for (int i = 0; i < 16; ++i) sum += local[i];
        lds[t] = sum;
        __syncthreads();
        for (int off = 1; off < 1024; off <<= 1) {
            unsigned int v = (t >= off) ? lds[t - off] : 0u;
            __syncthreads();
            lds[t] += v;
            __syncthreads();
        }
        unsigned int base = lds[t] - sum;   // exclusive base for this thread's bins
#pragma unroll
        for (int i = 0; i < 16; ++i) {
            offsets[t * 16 + i] = base;
            counts[t * 16 + i]  = base;     // cursor (aliases counts; own bins only)
            base += local[i];
        }
        if (t == 1023) offsets[M_ROWS] = lds[1023];
    }
    grid.sync();

    // phase 3: scatter into row-sorted order, 4 nnz/thread
    const int4   c4b = ((const int4*)(idx + NNZ_C))[tid];
    const float4 v4  = ((const float4*)vals)[tid];
    unsigned int p;
    p = atomicAdd(&counts[r4.x], 1u); pairs[p] = make_int2(c4b.x, __float_as_int(v4.x));
    p = atomicAdd(&counts[r4.y], 1u); pairs[p] = make_int2(c4b.y, __float_as_int(v4.y));
    p = atomicAdd(&counts[r4.z], 1u); pairs[p] = make_int2(c4b.z, __float_as_int(v4.z));
    p = atomicAdd(&counts[r4.w], 1u); pairs[p] = make_int2(c4b.w, __float_as_int(v4.w));
}

// ---------------- wave-per-row SpMM (unchanged control) ----------------
__global__ __launch_bounds__(256) void spmm_csr_kernel(const unsigned int* __restrict__ offsets,
                                                       const int2* __restrict__ pairs,
                                                       const float* __restrict__ B,
                                                       float* __restrict__ out) {
    const int row  = blockIdx.x * 4 + (threadIdx.x >> 6);   // wave = row
    const int lane = threadIdx.x & 63;

    unsigned int beg = __builtin_amdgcn_readfirstlane(offsets[row]);
    unsigned int end = __builtin_amdgcn_readfirstlane(offsets[row + 1]);

    const float4* __restrict__ B4 = (const float4*)B;
    float4 acc = make_float4(0.f, 0.f, 0.f, 0.f);

    for (unsigned int base_p = beg; base_p < end; base_p += 64) {
        const unsigned int p = base_p + lane;
        int pc = 0, pv = 0;
        if (p < end) {
            int2 pr = pairs[p];
            pc = pr.x;
            pv = pr.y;
        }
#pragma unroll 8
        for (int j = 0; j < 64; ++j) {
            const int   c = __builtin_amdgcn_readlane(pc, j);
            const float v = __int_as_float(__builtin_amdgcn_readlane(pv, j));
            const float4 b = B4[(size_t)c * 64 + lane];                // 1KB/wave gather
            acc.x += v * b.x;
            acc.y += v * b.y;
            acc.z += v * b.z;
            acc.w += v * b.w;
        }
    }
    ((float4*)out)[(size_t)row * 64 + lane] = acc;  // single coalesced 1KB/wave store
}

// ---------------- fallback if workspace too small ----------------
__global__ __launch_bounds__(256) void spmm_atomic_kernel(
    const float* __restrict__ vals, const int* __restrict__ idx,
    const float* __restrict__ B, float* __restrict__ out) {
    const int wave = (int)(blockIdx.x * 4 + (threadIdx.x >> 6));
    const int lane = (int)(threadIdx.x & 63);
    if (wave >= NNZ_C) return;
    const int r = idx[wave];
    const int c = idx[NNZ_C + wave];
    const float v = vals[wave];
    const float* brow = B + (size_t)c * NCOL;
    float* orow = out + (size_t)r * NCOL;
#pragma unroll
    for (int k = 0; k < 4; ++k) {
        const int col = lane + 64 * k;
        atomicAdd(&orow[col], v * brow[col]);
    }
}

extern "C" void kernel_launch(void* const* d_in, const int* in_sizes, int n_in,
                              void* d_out, int out_size, void* d_ws, size_t ws_size,
                              hipStream_t stream) {
    const float* A_values  = (const float*)d_in[0];
    const int*   A_indices = (const int*)d_in[1];   // int32 (JAX x64 disabled), [2, NNZ]
    const float* B         = (const float*)d_in[2];
    float*       out       = (float*)d_out;

    const size_t OFFSETS_OFF = 0;                       // 16385 u32
    const size_t COUNTS_OFF  = 66560;                   // 16384 u32 (becomes cursor)
    const size_t PAIRS_OFF   = COUNTS_OFF + 65536;
    const size_t NEEDED      = PAIRS_OFF + (size_t)NNZ_C * 8;  // ~8.5 MB

    if (ws_size < NEEDED) {
        hipMemsetAsync(d_out, 0, (size_t)out_size * sizeof(float), stream);
        spmm_atomic_kernel<<<NNZ_C / 4, 256, 0, stream>>>(A_values, A_indices, B, out);
        return;
    }

    uint8_t* w = (uint8_t*)d_ws;
    unsigned int* counts  = (unsigned int*)(w + COUNTS_OFF);
    unsigned int* offsets = (unsigned int*)(w + OFFSETS_OFF);
    int2*         pairs   = (int2*)(w + PAIRS_OFF);

    // fused zero+hist+scan+scatter: one cooperative dispatch (256 blocks x 1024 thr = NNZ/4)
    void* args[] = {(void*)&A_indices, (void*)&A_values, (void*)&counts,
                    (void*)&offsets, (void*)&pairs};
    hipLaunchCooperativeKernel((void*)build_csr_kernel, dim3(256), dim3(1024),
                               args, 0, stream);

    spmm_csr_kernel<<<M_ROWS / 4, 256, 0, stream>>>(offsets, pairs, B, out);
}

// Round 7
// 214.717 us; speedup vs baseline: 1.5777x; 1.5777x over previous
//
#include <hip/hip_runtime.h>
#include <stdint.h>

// SpMM: COO sparse A (16384x16384, 1,048,576 nnz) @ dense B (16384x256) -> out (16384x256)
// CSR-build (split dispatches; R6's cooperative fusion regressed) + wave-per-row SpMM.
//
// Round-7: B converted to bf16 in workspace (RNE), spmm processes 2 nnz per
// gather instruction (half-wave 0 -> nnz j, half-wave 1 -> nnz j+1; 16B/lane of
// 8 bf16). Halves BOTH candidate walls: gather bytes (1GB->0.5GB logical) and
// gather wave-instructions (1M->0.5M). fp32 accumulation, fp32 vals.

#define M_ROWS 16384
#define NNZ_C  1048576
#define NCOL   256

__device__ __forceinline__ float bf16_lo(unsigned int u) {
    return __uint_as_float(u << 16);
}
__device__ __forceinline__ float bf16_hi(unsigned int u) {
    return __uint_as_float(u & 0xffff0000u);
}

// ---------------- phase 0: B fp32 -> bf16 (RNE), 8 elems/thread ----------------
__global__ __launch_bounds__(256) void bconv_kernel(const float4* __restrict__ Bf,
                                                    uint4* __restrict__ Bh) {
    const int i = blockIdx.x * 256 + threadIdx.x;      // 524288 threads
    const float4 a = Bf[i * 2];
    const float4 b = Bf[i * 2 + 1];
    unsigned int w[8];
    const float src[8] = {a.x, a.y, a.z, a.w, b.x, b.y, b.z, b.w};
#pragma unroll
    for (int k = 0; k < 8; ++k) {
        unsigned int bits = __float_as_uint(src[k]);
        w[k] = (bits + 0x7fffu + ((bits >> 16) & 1u)) >> 16;   // RNE bf16
    }
    Bh[i] = make_uint4(w[0] | (w[1] << 16), w[2] | (w[3] << 16),
                       w[4] | (w[5] << 16), w[6] | (w[7] << 16));
}

// ---------------- phase 1: histogram (4 nnz/thread) ----------------
__global__ __launch_bounds__(256) void hist_kernel(const int* __restrict__ idx,
                                                   unsigned int* __restrict__ counts) {
    const int i = blockIdx.x * 256 + threadIdx.x;
    const int4 r4 = ((const int4*)idx)[i];
    atomicAdd(&counts[r4.x], 1u);
    atomicAdd(&counts[r4.y], 1u);
    atomicAdd(&counts[r4.z], 1u);
    atomicAdd(&counts[r4.w], 1u);
}

// ---------------- phase 2: exclusive scan (1 block, 1024 thr x 16 bins) ----------------
__global__ __launch_bounds__(1024) void scan_kernel(const unsigned int* __restrict__ counts,
                                                    unsigned int* __restrict__ offsets,
                                                    unsigned int* __restrict__ cursor) {
    __shared__ unsigned int lds[1024];
    const int t = threadIdx.x;
    const uint4* c4 = (const uint4*)counts;
    uint4 L[4];
#pragma unroll
    for (int k = 0; k < 4; ++k) L[k] = c4[t * 4 + k];
    unsigned int local[16];
#pragma unroll
    for (int k = 0; k < 4; ++k) {
        local[k * 4 + 0] = L[k].x;
        local[k * 4 + 1] = L[k].y;
        local[k * 4 + 2] = L[k].z;
        local[k * 4 + 3] = L[k].w;
    }
    unsigned int sum = 0;
#pragma unroll
    for (int i = 0; i < 16; ++i) sum += local[i];
    lds[t] = sum;
    __syncthreads();
    for (int off = 1; off < 1024; off <<= 1) {
        unsigned int v = (t >= off) ? lds[t - off] : 0u;
        __syncthreads();
        lds[t] += v;
        __syncthreads();
    }
    unsigned int base = lds[t] - sum;
#pragma unroll
    for (int i = 0; i < 16; ++i) {
        offsets[t * 16 + i] = base;
        cursor[t * 16 + i]  = base;
        base += local[i];
    }
    if (t == 1023) offsets[M_ROWS] = lds[1023];
}

// ---------------- phase 3: scatter (4 nnz/thread) ----------------
__global__ __launch_bounds__(256) void scatter_kernel(const int* __restrict__ idx,
                                                      const float* __restrict__ vals,
                                                      unsigned int* __restrict__ cursor,
                                                      int2* __restrict__ pairs) {
    const int i = blockIdx.x * 256 + threadIdx.x;
    const int4   r4 = ((const int4*)idx)[i];
    const int4   c4 = ((const int4*)(idx + NNZ_C))[i];
    const float4 v4 = ((const float4*)vals)[i];
    unsigned int p;
    p = atomicAdd(&cursor[r4.x], 1u); pairs[p] = make_int2(c4.x, __float_as_int(v4.x));
    p = atomicAdd(&cursor[r4.y], 1u); pairs[p] = make_int2(c4.y, __float_as_int(v4.y));
    p = atomicAdd(&cursor[r4.z], 1u); pairs[p] = make_int2(c4.z, __float_as_int(v4.z));
    p = atomicAdd(&cursor[r4.w], 1u); pairs[p] = make_int2(c4.w, __float_as_int(v4.w));
}

// ---------------- phase 4: wave-per-row SpMM, bf16 B, 2 nnz per gather ----------------
__global__ __launch_bounds__(256) void spmm_bf16_kernel(const unsigned int* __restrict__ offsets,
                                                        const int2* __restrict__ pairs,
                                                        const unsigned short* __restrict__ Bh,
                                                        float* __restrict__ out) {
    const int row  = blockIdx.x * 4 + (threadIdx.x >> 6);   // wave = row
    const int lane = threadIdx.x & 63;
    const int half = lane >> 5;                              // 0 -> nnz j, 1 -> nnz j+1
    const int sub  = lane & 31;                              // owns cols [sub*8, sub*8+8)

    unsigned int beg = __builtin_amdgcn_readfirstlane(offsets[row]);
    unsigned int end = __builtin_amdgcn_readfirstlane(offsets[row + 1]);

    const uint4* __restrict__ B16 = (const uint4*)Bh;        // bf16 row = 512B = 32 uint4
    float acc[8] = {0.f, 0.f, 0.f, 0.f, 0.f, 0.f, 0.f, 0.f};

    for (unsigned int base_p = beg; base_p < end; base_p += 64) {
        const unsigned int p = base_p + lane;
        int pc = 0, pv = 0;
        if (p < end) {                      // OOB lanes -> (col 0, val 0): zero contribution
            int2 pr = pairs[p];
            pc = pr.x;
            pv = pr.y;
        }
#pragma unroll 8
        for (int j = 0; j < 64; j += 2) {
            const int   c0 = __builtin_amdgcn_readlane(pc, j);
            const float v0 = __int_as_float(__builtin_amdgcn_readlane(pv, j));
            const int   c1 = __builtin_amdgcn_readlane(pc, j + 1);
            const float v1 = __int_as_float(__builtin_amdgcn_readlane(pv, j + 1));
            const int   c = half ? c1 : c0;
            const float v = half ? v1 : v0;
            const uint4 b = B16[(size_t)c * 32 + sub];       // 16B/lane, 1KB/wave for 2 nnz
            acc[0] += v * bf16_lo(b.x);
            acc[1] += v * bf16_hi(b.x);
            acc[2] += v * bf16_lo(b.y);
            acc[3] += v * bf16_hi(b.y);
            acc[4] += v * bf16_lo(b.z);
            acc[5] += v * bf16_hi(b.z);
            acc[6] += v * bf16_lo(b.w);
            acc[7] += v * bf16_hi(b.w);
        }
    }

    // cross-half reduce: lane L and L+32 hold partials for the same 8 columns
#pragma unroll
    for (int k = 0; k < 8; ++k) acc[k] += __shfl_xor(acc[k], 32, 64);

    if (half == 0) {                        // lanes 0..31 store the 1KB row
        float* o = out + (size_t)row * NCOL + sub * 8;
        *(float4*)(o)     = make_float4(acc[0], acc[1], acc[2], acc[3]);
        *(float4*)(o + 4) = make_float4(acc[4], acc[5], acc[6], acc[7]);
    }
}

// ---------------- fp32 spmm (fallback tier 1, R5 kernel) ----------------
__global__ __launch_bounds__(256) void spmm_csr_kernel(const unsigned int* __restrict__ offsets,
                                                       const int2* __restrict__ pairs,
                                                       const float* __restrict__ B,
                                                       float* __restrict__ out) {
    const int row  = blockIdx.x * 4 + (threadIdx.x >> 6);
    const int lane = threadIdx.x & 63;
    unsigned int beg = __builtin_amdgcn_readfirstlane(offsets[row]);
    unsigned int end = __builtin_amdgcn_readfirstlane(offsets[row + 1]);
    const float4* __restrict__ B4 = (const float4*)B;
    float4 acc = make_float4(0.f, 0.f, 0.f, 0.f);
    for (unsigned int base_p = beg; base_p < end; base_p += 64) {
        const unsigned int p = base_p + lane;
        int pc = 0, pv = 0;
        if (p < end) { int2 pr = pairs[p]; pc = pr.x; pv = pr.y; }
#pragma unroll 8
        for (int j = 0; j < 64; ++j) {
            const int   c = __builtin_amdgcn_readlane(pc, j);
            const float v = __int_as_float(__builtin_amdgcn_readlane(pv, j));
            const float4 b = B4[(size_t)c * 64 + lane];
            acc.x += v * b.x; acc.y += v * b.y; acc.z += v * b.z; acc.w += v * b.w;
        }
    }
    ((float4*)out)[(size_t)row * 64 + lane] = acc;
}

// ---------------- atomic fallback (tier 2) ----------------
__global__ __launch_bounds__(256) void spmm_atomic_kernel(
    const float* __restrict__ vals, const int* __restrict__ idx,
    const float* __restrict__ B, float* __restrict__ out) {
    const int wave = (int)(blockIdx.x * 4 + (threadIdx.x >> 6));
    const int lane = (int)(threadIdx.x & 63);
    if (wave >= NNZ_C) return;
    const int r = idx[wave];
    const int c = idx[NNZ_C + wave];
    const float v = vals[wave];
    const float* brow = B + (size_t)c * NCOL;
    float* orow = out + (size_t)r * NCOL;
#pragma unroll
    for (int k = 0; k < 4; ++k) {
        const int col = lane + 64 * k;
        atomicAdd(&orow[col], v * brow[col]);
    }
}

extern "C" void kernel_launch(void* const* d_in, const int* in_sizes, int n_in,
                              void* d_out, int out_size, void* d_ws, size_t ws_size,
                              hipStream_t stream) {
    const float* A_values  = (const float*)d_in[0];
    const int*   A_indices = (const int*)d_in[1];   // int32 (JAX x64 disabled), [2, NNZ]
    const float* B         = (const float*)d_in[2];
    float*       out       = (float*)d_out;

    // workspace layout
    const size_t OFFSETS_OFF = 0;                               // 16385 u32
    const size_t COUNTS_OFF  = 66560;                           // 16384 u32 (becomes cursor)
    const size_t PAIRS_OFF   = COUNTS_OFF + 65536;              // 8 MB
    const size_t BH_OFF      = PAIRS_OFF + (size_t)NNZ_C * 8;   // 8 MB bf16 B
    const size_t NEED_FP32   = BH_OFF;                          // ~8.5 MB
    const size_t NEED_BF16   = BH_OFF + (size_t)M_ROWS * NCOL * 2;

    if (ws_size < NEED_FP32) {
        hipMemsetAsync(d_out, 0, (size_t)out_size * sizeof(float), stream);
        spmm_atomic_kernel<<<NNZ_C / 4, 256, 0, stream>>>(A_values, A_indices, B, out);
        return;
    }

    uint8_t* w = (uint8_t*)d_ws;
    unsigned int*   offsets = (unsigned int*)(w + OFFSETS_OFF);
    unsigned int*   counts  = (unsigned int*)(w + COUNTS_OFF);  // also cursor
    int2*           pairs   = (int2*)(w + PAIRS_OFF);
    unsigned short* Bh      = (unsigned short*)(w + BH_OFF);

    const bool use_bf16 = (ws_size >= NEED_BF16);

    if (use_bf16) {
        // 4,194,304 elems / 8 per thread = 524,288 threads
        bconv_kernel<<<2048, 256, 0, stream>>>((const float4*)B, (uint4*)Bh);
    }
    hipMemsetAsync(counts, 0, M_ROWS * sizeof(unsigned int), stream);
    hist_kernel<<<NNZ_C / 4 / 256, 256, 0, stream>>>(A_indices, counts);
    scan_kernel<<<1, 1024, 0, stream>>>(counts, offsets, counts /*cursor*/);
    scatter_kernel<<<NNZ_C / 4 / 256, 256, 0, stream>>>(A_indices, A_values, counts, pairs);

    if (use_bf16) {
        spmm_bf16_kernel<<<M_ROWS / 4, 256, 0, stream>>>(offsets, pairs, Bh, out);
    } else {
        spmm_csr_kernel<<<M_ROWS / 4, 256, 0, stream>>>(offsets, pairs, B, out);
    }
}

// Round 8
// 210.286 us; speedup vs baseline: 1.6110x; 1.0211x over previous
//
#include <hip/hip_runtime.h>
#include <stdint.h>

// SpMM: COO sparse A (16384x16384, 1,048,576 nnz) @ dense B (16384x256) -> out (16384x256)
// CSR-build + wave-per-row bf16 SpMM (2 nnz/gather).
//
// Round-8: XCD-sharded hist & scatter. R7 counters showed scatter at 83us with
// WRITE_SIZE 63.5MB = one full-line writeback per 8B store (cross-XCD line
// ping-pong on pairs/cursor lines). Fix: blocks (shard=blockIdx&7, chunk=
// blockIdx>>3) read the full COO stream but only process rows in their shard
// (row>>11==shard), so every cursor/pairs line is owned by ONE XCD (blockIdx%8
// round-robin heuristic). Reads are 8x-replicated but L2/LLC-absorbed.

#define M_ROWS 16384
#define NNZ_C  1048576
#define NCOL   256
#define NSHARD 8
#define SHARD_ROWS 2048            // M_ROWS / NSHARD
#define CHUNKS 256                 // nnz chunks; CHUNK_NNZ = NNZ_C/CHUNKS = 4096

__device__ __forceinline__ float bf16_lo(unsigned int u) { return __uint_as_float(u << 16); }
__device__ __forceinline__ float bf16_hi(unsigned int u) { return __uint_as_float(u & 0xffff0000u); }

// ---------------- phase 0: B fp32 -> bf16 (RNE), 8 elems/thread ----------------
__global__ __launch_bounds__(256) void bconv_kernel(const float4* __restrict__ Bf,
                                                    uint4* __restrict__ Bh) {
    const int i = blockIdx.x * 256 + threadIdx.x;      // 524288 threads
    const float4 a = Bf[i * 2];
    const float4 b = Bf[i * 2 + 1];
    unsigned int w[8];
    const float src[8] = {a.x, a.y, a.z, a.w, b.x, b.y, b.z, b.w};
#pragma unroll
    for (int k = 0; k < 8; ++k) {
        unsigned int bits = __float_as_uint(src[k]);
        w[k] = (bits + 0x7fffu + ((bits >> 16) & 1u)) >> 16;   // RNE bf16
    }
    Bh[i] = make_uint4(w[0] | (w[1] << 16), w[2] | (w[3] << 16),
                       w[4] | (w[5] << 16), w[6] | (w[7] << 16));
}

// ---------------- phase 1: XCD-sharded histogram ----------------
// grid 2048 = 256 chunks x 8 shards; block handles 4096 nnz, counts only its shard's rows.
__global__ __launch_bounds__(256) void hist_sharded_kernel(const int* __restrict__ idx,
                                                           unsigned int* __restrict__ counts) {
    const int shard = blockIdx.x & (NSHARD - 1);       // == XCD id under %8 round-robin
    const int chunk = blockIdx.x >> 3;
    const int rlo   = shard * SHARD_ROWS;
#pragma unroll
    for (int k = 0; k < 4; ++k) {
        const int i4 = chunk * 1024 + k * 256 + threadIdx.x;
        const int4 r4 = ((const int4*)idx)[i4];
        if ((unsigned)(r4.x - rlo) < SHARD_ROWS) atomicAdd(&counts[r4.x], 1u);
        if ((unsigned)(r4.y - rlo) < SHARD_ROWS) atomicAdd(&counts[r4.y], 1u);
        if ((unsigned)(r4.z - rlo) < SHARD_ROWS) atomicAdd(&counts[r4.z], 1u);
        if ((unsigned)(r4.w - rlo) < SHARD_ROWS) atomicAdd(&counts[r4.w], 1u);
    }
}

// ---------------- phase 2: exclusive scan (1 block, 1024 thr x 16 bins) ----------------
__global__ __launch_bounds__(1024) void scan_kernel(const unsigned int* __restrict__ counts,
                                                    unsigned int* __restrict__ offsets,
                                                    unsigned int* __restrict__ cursor) {
    __shared__ unsigned int lds[1024];
    const int t = threadIdx.x;
    const uint4* c4 = (const uint4*)counts;
    uint4 L[4];
#pragma unroll
    for (int k = 0; k < 4; ++k) L[k] = c4[t * 4 + k];
    unsigned int local[16];
#pragma unroll
    for (int k = 0; k < 4; ++k) {
        local[k * 4 + 0] = L[k].x;
        local[k * 4 + 1] = L[k].y;
        local[k * 4 + 2] = L[k].z;
        local[k * 4 + 3] = L[k].w;
    }
    unsigned int sum = 0;
#pragma unroll
    for (int i = 0; i < 16; ++i) sum += local[i];
    lds[t] = sum;
    __syncthreads();
    for (int off = 1; off < 1024; off <<= 1) {
        unsigned int v = (t >= off) ? lds[t - off] : 0u;
        __syncthreads();
        lds[t] += v;
        __syncthreads();
    }
    unsigned int base = lds[t] - sum;
#pragma unroll
    for (int i = 0; i < 16; ++i) {
        offsets[t * 16 + i] = base;
        cursor[t * 16 + i]  = base;
        base += local[i];
    }
    if (t == 1023) offsets[M_ROWS] = lds[1023];
}

// ---------------- phase 3: XCD-sharded scatter ----------------
__global__ __launch_bounds__(256) void scatter_sharded_kernel(const int* __restrict__ idx,
                                                              const float* __restrict__ vals,
                                                              unsigned int* __restrict__ cursor,
                                                              int2* __restrict__ pairs) {
    const int shard = blockIdx.x & (NSHARD - 1);
    const int chunk = blockIdx.x >> 3;
    const int rlo   = shard * SHARD_ROWS;
#pragma unroll
    for (int k = 0; k < 4; ++k) {
        const int i4 = chunk * 1024 + k * 256 + threadIdx.x;
        const int4   r4 = ((const int4*)idx)[i4];
        const int4   c4 = ((const int4*)(idx + NNZ_C))[i4];
        const float4 v4 = ((const float4*)vals)[i4];
        unsigned int p;
        if ((unsigned)(r4.x - rlo) < SHARD_ROWS) {
            p = atomicAdd(&cursor[r4.x], 1u); pairs[p] = make_int2(c4.x, __float_as_int(v4.x));
        }
        if ((unsigned)(r4.y - rlo) < SHARD_ROWS) {
            p = atomicAdd(&cursor[r4.y], 1u); pairs[p] = make_int2(c4.y, __float_as_int(v4.y));
        }
        if ((unsigned)(r4.z - rlo) < SHARD_ROWS) {
            p = atomicAdd(&cursor[r4.z], 1u); pairs[p] = make_int2(c4.z, __float_as_int(v4.z));
        }
        if ((unsigned)(r4.w - rlo) < SHARD_ROWS) {
            p = atomicAdd(&cursor[r4.w], 1u); pairs[p] = make_int2(c4.w, __float_as_int(v4.w));
        }
    }
}

// ---------------- phase 4: wave-per-row SpMM, bf16 B, 2 nnz per gather (control) ----------------
__global__ __launch_bounds__(256) void spmm_bf16_kernel(const unsigned int* __restrict__ offsets,
                                                        const int2* __restrict__ pairs,
                                                        const unsigned short* __restrict__ Bh,
                                                        float* __restrict__ out) {
    const int row  = blockIdx.x * 4 + (threadIdx.x >> 6);   // wave = row
    const int lane = threadIdx.x & 63;
    const int half = lane >> 5;
    const int sub  = lane & 31;

    unsigned int beg = __builtin_amdgcn_readfirstlane(offsets[row]);
    unsigned int end = __builtin_amdgcn_readfirstlane(offsets[row + 1]);

    const uint4* __restrict__ B16 = (const uint4*)Bh;
    float acc[8] = {0.f, 0.f, 0.f, 0.f, 0.f, 0.f, 0.f, 0.f};

    for (unsigned int base_p = beg; base_p < end; base_p += 64) {
        const unsigned int p = base_p + lane;
        int pc = 0, pv = 0;
        if (p < end) {
            int2 pr = pairs[p];
            pc = pr.x;
            pv = pr.y;
        }
#pragma unroll 8
        for (int j = 0; j < 64; j += 2) {
            const int   c0 = __builtin_amdgcn_readlane(pc, j);
            const float v0 = __int_as_float(__builtin_amdgcn_readlane(pv, j));
            const int   c1 = __builtin_amdgcn_readlane(pc, j + 1);
            const float v1 = __int_as_float(__builtin_amdgcn_readlane(pv, j + 1));
            const int   c = half ? c1 : c0;
            const float v = half ? v1 : v0;
            const uint4 b = B16[(size_t)c * 32 + sub];       // 16B/lane, 1KB/wave for 2 nnz
            acc[0] += v * bf16_lo(b.x);
            acc[1] += v * bf16_hi(b.x);
            acc[2] += v * bf16_lo(b.y);
            acc[3] += v * bf16_hi(b.y);
            acc[4] += v * bf16_lo(b.z);
            acc[5] += v * bf16_hi(b.z);
            acc[6] += v * bf16_lo(b.w);
            acc[7] += v * bf16_hi(b.w);
        }
    }
#pragma unroll
    for (int k = 0; k < 8; ++k) acc[k] += __shfl_xor(acc[k], 32, 64);

    if (half == 0) {
        float* o = out + (size_t)row * NCOL + sub * 8;
        *(float4*)(o)     = make_float4(acc[0], acc[1], acc[2], acc[3]);
        *(float4*)(o + 4) = make_float4(acc[4], acc[5], acc[6], acc[7]);
    }
}

// ---------------- fp32 spmm (fallback tier 1) ----------------
__global__ __launch_bounds__(256) void spmm_csr_kernel(const unsigned int* __restrict__ offsets,
                                                       const int2* __restrict__ pairs,
                                                       const float* __restrict__ B,
                                                       float* __restrict__ out) {
    const int row  = blockIdx.x * 4 + (threadIdx.x >> 6);
    const int lane = threadIdx.x & 63;
    unsigned int beg = __builtin_amdgcn_readfirstlane(offsets[row]);
    unsigned int end = __builtin_amdgcn_readfirstlane(offsets[row + 1]);
    const float4* __restrict__ B4 = (const float4*)B;
    float4 acc = make_float4(0.f, 0.f, 0.f, 0.f);
    for (unsigned int base_p = beg; base_p < end; base_p += 64) {
        const unsigned int p = base_p + lane;
        int pc = 0, pv = 0;
        if (p < end) { int2 pr = pairs[p]; pc = pr.x; pv = pr.y; }
#pragma unroll 8
        for (int j = 0; j < 64; ++j) {
            const int   c = __builtin_amdgcn_readlane(pc, j);
            const float v = __int_as_float(__builtin_amdgcn_readlane(pv, j));
            const float4 b = B4[(size_t)c * 64 + lane];
            acc.x += v * b.x; acc.y += v * b.y; acc.z += v * b.z; acc.w += v * b.w;
        }
    }
    ((float4*)out)[(size_t)row * 64 + lane] = acc;
}

// ---------------- atomic fallback (tier 2) ----------------
__global__ __launch_bounds__(256) void spmm_atomic_kernel(
    const float* __restrict__ vals, const int* __restrict__ idx,
    const float* __restrict__ B, float* __restrict__ out) {
    const int wave = (int)(blockIdx.x * 4 + (threadIdx.x >> 6));
    const int lane = (int)(threadIdx.x & 63);
    if (wave >= NNZ_C) return;
    const int r = idx[wave];
    const int c = idx[NNZ_C + wave];
    const float v = vals[wave];
    const float* brow = B + (size_t)c * NCOL;
    float* orow = out + (size_t)r * NCOL;
#pragma unroll
    for (int k = 0; k < 4; ++k) {
        const int col = lane + 64 * k;
        atomicAdd(&orow[col], v * brow[col]);
    }
}

extern "C" void kernel_launch(void* const* d_in, const int* in_sizes, int n_in,
                              void* d_out, int out_size, void* d_ws, size_t ws_size,
                              hipStream_t stream) {
    const float* A_values  = (const float*)d_in[0];
    const int*   A_indices = (const int*)d_in[1];   // int32 (JAX x64 disabled), [2, NNZ]
    const float* B         = (const float*)d_in[2];
    float*       out       = (float*)d_out;

    // workspace layout
    const size_t OFFSETS_OFF = 0;                               // 16385 u32
    const size_t COUNTS_OFF  = 66560;                           // 16384 u32 (becomes cursor)
    const size_t PAIRS_OFF   = COUNTS_OFF + 65536;              // 8 MB
    const size_t BH_OFF      = PAIRS_OFF + (size_t)NNZ_C * 8;   // 8 MB bf16 B
    const size_t NEED_FP32   = BH_OFF;                          // ~8.5 MB
    const size_t NEED_BF16   = BH_OFF + (size_t)M_ROWS * NCOL * 2;

    if (ws_size < NEED_FP32) {
        hipMemsetAsync(d_out, 0, (size_t)out_size * sizeof(float), stream);
        spmm_atomic_kernel<<<NNZ_C / 4, 256, 0, stream>>>(A_values, A_indices, B, out);
        return;
    }

    uint8_t* w = (uint8_t*)d_ws;
    unsigned int*   offsets = (unsigned int*)(w + OFFSETS_OFF);
    unsigned int*   counts  = (unsigned int*)(w + COUNTS_OFF);  // also cursor
    int2*           pairs   = (int2*)(w + PAIRS_OFF);
    unsigned short* Bh      = (unsigned short*)(w + BH_OFF);

    const bool use_bf16 = (ws_size >= NEED_BF16);

    if (use_bf16) {
        bconv_kernel<<<2048, 256, 0, stream>>>((const float4*)B, (uint4*)Bh);
    }
    hipMemsetAsync(counts, 0, M_ROWS * sizeof(unsigned int), stream);
    hist_sharded_kernel<<<CHUNKS * NSHARD, 256, 0, stream>>>(A_indices, counts);
    scan_kernel<<<1, 1024, 0, stream>>>(counts, offsets, counts /*cursor*/);
    scatter_sharded_kernel<<<CHUNKS * NSHARD, 256, 0, stream>>>(A_indices, A_values, counts, pairs);

    if (use_bf16) {
        spmm_bf16_kernel<<<M_ROWS / 4, 256, 0, stream>>>(offsets, pairs, Bh, out);
    } else {
        spmm_csr_kernel<<<M_ROWS / 4, 256, 0, stream>>>(offsets, pairs, B, out);
    }
}

// Round 9
// 210.182 us; speedup vs baseline: 1.6118x; 1.0005x over previous
//
#include <hip/hip_runtime.h>
#include <stdint.h>

// SpMM: COO sparse A (16384x16384, 1,048,576 nnz) @ dense B (16384x256) -> out (16384x256)
// CSR-build (XCD-sharded) + wave-per-row bf16 SpMM (2 nnz/gather).
//
// Round-9: non-temporal loads on all streamed read-once inputs.
// R8 counters: scatter WRITE 63.5->43MB after sharding — residual amplification
// attributed to the 12MB replicated idx/vals READ STREAM evicting the
// partially-filled pairs lines from the owning XCD's 4MB L2 (pairs shard is
// only 1MB; without read pressure it would write back once = 8MB total).
// nt loads (L2 no-allocate) keep the victim lines resident. Also nt on spmm's
// sequential pairs stream so it stops evicting hot bf16-B lines.

#define M_ROWS 16384
#define NNZ_C  1048576
#define NCOL   256
#define NSHARD 8
#define SHARD_ROWS 2048            // M_ROWS / NSHARD
#define CHUNKS 256                 // nnz chunks; CHUNK_NNZ = NNZ_C/CHUNKS = 4096

typedef int   vint4   __attribute__((ext_vector_type(4)));
typedef float vfloat4 __attribute__((ext_vector_type(4)));
typedef int   vint2   __attribute__((ext_vector_type(2)));

__device__ __forceinline__ float bf16_lo(unsigned int u) { return __uint_as_float(u << 16); }
__device__ __forceinline__ float bf16_hi(unsigned int u) { return __uint_as_float(u & 0xffff0000u); }

// ---------------- phase 0: B fp32 -> bf16 (RNE), 8 elems/thread ----------------
__global__ __launch_bounds__(256) void bconv_kernel(const float4* __restrict__ Bf,
                                                    uint4* __restrict__ Bh) {
    const int i = blockIdx.x * 256 + threadIdx.x;      // 524288 threads
    const float4 a = Bf[i * 2];
    const float4 b = Bf[i * 2 + 1];
    unsigned int w[8];
    const float src[8] = {a.x, a.y, a.z, a.w, b.x, b.y, b.z, b.w};
#pragma unroll
    for (int k = 0; k < 8; ++k) {
        unsigned int bits = __float_as_uint(src[k]);
        w[k] = (bits + 0x7fffu + ((bits >> 16) & 1u)) >> 16;   // RNE bf16
    }
    Bh[i] = make_uint4(w[0] | (w[1] << 16), w[2] | (w[3] << 16),
                       w[4] | (w[5] << 16), w[6] | (w[7] << 16));
}

// ---------------- phase 1: XCD-sharded histogram (nt reads) ----------------
__global__ __launch_bounds__(256) void hist_sharded_kernel(const int* __restrict__ idx,
                                                           unsigned int* __restrict__ counts) {
    const int shard = blockIdx.x & (NSHARD - 1);       // == XCD id under %8 round-robin
    const int chunk = blockIdx.x >> 3;
    const int rlo   = shard * SHARD_ROWS;
#pragma unroll
    for (int k = 0; k < 4; ++k) {
        const int i4 = chunk * 1024 + k * 256 + threadIdx.x;
        const vint4 r4 = __builtin_nontemporal_load(((const vint4*)idx) + i4);
        if ((unsigned)(r4.x - rlo) < SHARD_ROWS) atomicAdd(&counts[r4.x], 1u);
        if ((unsigned)(r4.y - rlo) < SHARD_ROWS) atomicAdd(&counts[r4.y], 1u);
        if ((unsigned)(r4.z - rlo) < SHARD_ROWS) atomicAdd(&counts[r4.z], 1u);
        if ((unsigned)(r4.w - rlo) < SHARD_ROWS) atomicAdd(&counts[r4.w], 1u);
    }
}

// ---------------- phase 2: exclusive scan (1 block, 1024 thr x 16 bins) ----------------
__global__ __launch_bounds__(1024) void scan_kernel(const unsigned int* __restrict__ counts,
                                                    unsigned int* __restrict__ offsets,
                                                    unsigned int* __restrict__ cursor) {
    __shared__ unsigned int lds[1024];
    const int t = threadIdx.x;
    const uint4* c4 = (const uint4*)counts;
    uint4 L[4];
#pragma unroll
    for (int k = 0; k < 4; ++k) L[k] = c4[t * 4 + k];
    unsigned int local[16];
#pragma unroll
    for (int k = 0; k < 4; ++k) {
        local[k * 4 + 0] = L[k].x;
        local[k * 4 + 1] = L[k].y;
        local[k * 4 + 2] = L[k].z;
        local[k * 4 + 3] = L[k].w;
    }
    unsigned int sum = 0;
#pragma unroll
    for (int i = 0; i < 16; ++i) sum += local[i];
    lds[t] = sum;
    __syncthreads();
    for (int off = 1; off < 1024; off <<= 1) {
        unsigned int v = (t >= off) ? lds[t - off] : 0u;
        __syncthreads();
        lds[t] += v;
        __syncthreads();
    }
    unsigned int base = lds[t] - sum;
#pragma unroll
    for (int i = 0; i < 16; ++i) {
        offsets[t * 16 + i] = base;
        cursor[t * 16 + i]  = base;
        base += local[i];
    }
    if (t == 1023) offsets[M_ROWS] = lds[1023];
}

// ---------------- phase 3: XCD-sharded scatter (nt reads) ----------------
__global__ __launch_bounds__(256) void scatter_sharded_kernel(const int* __restrict__ idx,
                                                              const float* __restrict__ vals,
                                                              unsigned int* __restrict__ cursor,
                                                              int2* __restrict__ pairs) {
    const int shard = blockIdx.x & (NSHARD - 1);
    const int chunk = blockIdx.x >> 3;
    const int rlo   = shard * SHARD_ROWS;
#pragma unroll
    for (int k = 0; k < 4; ++k) {
        const int i4 = chunk * 1024 + k * 256 + threadIdx.x;
        const vint4   r4 = __builtin_nontemporal_load(((const vint4*)idx) + i4);
        const vint4   c4 = __builtin_nontemporal_load(((const vint4*)(idx + NNZ_C)) + i4);
        const vfloat4 v4 = __builtin_nontemporal_load(((const vfloat4*)vals) + i4);
        unsigned int p;
        if ((unsigned)(r4.x - rlo) < SHARD_ROWS) {
            p = atomicAdd(&cursor[r4.x], 1u); pairs[p] = make_int2(c4.x, __float_as_int(v4.x));
        }
        if ((unsigned)(r4.y - rlo) < SHARD_ROWS) {
            p = atomicAdd(&cursor[r4.y], 1u); pairs[p] = make_int2(c4.y, __float_as_int(v4.y));
        }
        if ((unsigned)(r4.z - rlo) < SHARD_ROWS) {
            p = atomicAdd(&cursor[r4.z], 1u); pairs[p] = make_int2(c4.z, __float_as_int(v4.z));
        }
        if ((unsigned)(r4.w - rlo) < SHARD_ROWS) {
            p = atomicAdd(&cursor[r4.w], 1u); pairs[p] = make_int2(c4.w, __float_as_int(v4.w));
        }
    }
}

// ---------------- phase 4: wave-per-row SpMM, bf16 B, 2 nnz/gather, nt pairs ----------------
__global__ __launch_bounds__(256) void spmm_bf16_kernel(const unsigned int* __restrict__ offsets,
                                                        const int2* __restrict__ pairs,
                                                        const unsigned short* __restrict__ Bh,
                                                        float* __restrict__ out) {
    const int row  = blockIdx.x * 4 + (threadIdx.x >> 6);   // wave = row
    const int lane = threadIdx.x & 63;
    const int half = lane >> 5;
    const int sub  = lane & 31;

    unsigned int beg = __builtin_amdgcn_readfirstlane(offsets[row]);
    unsigned int end = __builtin_amdgcn_readfirstlane(offsets[row + 1]);

    const uint4* __restrict__ B16 = (const uint4*)Bh;
    float acc[8] = {0.f, 0.f, 0.f, 0.f, 0.f, 0.f, 0.f, 0.f};

    for (unsigned int base_p = beg; base_p < end; base_p += 64) {
        const unsigned int p = base_p + lane;
        int pc = 0, pv = 0;
        if (p < end) {
            // nt: pairs is a read-once stream; don't evict hot bf16-B lines from L2
            const vint2 pr = __builtin_nontemporal_load(((const vint2*)pairs) + p);
            pc = pr.x;
            pv = pr.y;
        }
#pragma unroll 8
        for (int j = 0; j < 64; j += 2) {
            const int   c0 = __builtin_amdgcn_readlane(pc, j);
            const float v0 = __int_as_float(__builtin_amdgcn_readlane(pv, j));
            const int   c1 = __builtin_amdgcn_readlane(pc, j + 1);
            const float v1 = __int_as_float(__builtin_amdgcn_readlane(pv, j + 1));
            const int   c = half ? c1 : c0;
            const float v = half ? v1 : v0;
            const uint4 b = B16[(size_t)c * 32 + sub];       // 16B/lane, 1KB/wave for 2 nnz
            acc[0] += v * bf16_lo(b.x);
            acc[1] += v * bf16_hi(b.x);
            acc[2] += v * bf16_lo(b.y);
            acc[3] += v * bf16_hi(b.y);
            acc[4] += v * bf16_lo(b.z);
            acc[5] += v * bf16_hi(b.z);
            acc[6] += v * bf16_lo(b.w);
            acc[7] += v * bf16_hi(b.w);
        }
    }
#pragma unroll
    for (int k = 0; k < 8; ++k) acc[k] += __shfl_xor(acc[k], 32, 64);

    if (half == 0) {
        float* o = out + (size_t)row * NCOL + sub * 8;
        *(float4*)(o)     = make_float4(acc[0], acc[1], acc[2], acc[3]);
        *(float4*)(o + 4) = make_float4(acc[4], acc[5], acc[6], acc[7]);
    }
}

// ---------------- fp32 spmm (fallback tier 1) ----------------
__global__ __launch_bounds__(256) void spmm_csr_kernel(const unsigned int* __restrict__ offsets,
                                                       const int2* __restrict__ pairs,
                                                       const float* __restrict__ B,
                                                       float* __restrict__ out) {
    const int row  = blockIdx.x * 4 + (threadIdx.x >> 6);
    const int lane = threadIdx.x & 63;
    unsigned int beg = __builtin_amdgcn_readfirstlane(offsets[row]);
    unsigned int end = __builtin_amdgcn_readfirstlane(offsets[row + 1]);
    const float4* __restrict__ B4 = (const float4*)B;
    float4 acc = make_float4(0.f, 0.f, 0.f, 0.f);
    for (unsigned int base_p = beg; base_p < end; base_p += 64) {
        const unsigned int p = base_p + lane;
        int pc = 0, pv = 0;
        if (p < end) { int2 pr = pairs[p]; pc = pr.x; pv = pr.y; }
#pragma unroll 8
        for (int j = 0; j < 64; ++j) {
            const int   c = __builtin_amdgcn_readlane(pc, j);
            const float v = __int_as_float(__builtin_amdgcn_readlane(pv, j));
            const float4 b = B4[(size_t)c * 64 + lane];
            acc.x += v * b.x; acc.y += v * b.y; acc.z += v * b.z; acc.w += v * b.w;
        }
    }
    ((float4*)out)[(size_t)row * 64 + lane] = acc;
}

// ---------------- atomic fallback (tier 2) ----------------
__global__ __launch_bounds__(256) void spmm_atomic_kernel(
    const float* __restrict__ vals, const int* __restrict__ idx,
    const float* __restrict__ B, float* __restrict__ out) {
    const int wave = (int)(blockIdx.x * 4 + (threadIdx.x >> 6));
    const int lane = (int)(threadIdx.x & 63);
    if (wave >= NNZ_C) return;
    const int r = idx[wave];
    const int c = idx[NNZ_C + wave];
    const float v = vals[wave];
    const float* brow = B + (size_t)c * NCOL;
    float* orow = out + (size_t)r * NCOL;
#pragma unroll
    for (int k = 0; k < 4; ++k) {
        const int col = lane + 64 * k;
        atomicAdd(&orow[col], v * brow[col]);
    }
}

extern "C" void kernel_launch(void* const* d_in, const int* in_sizes, int n_in,
                              void* d_out, int out_size, void* d_ws, size_t ws_size,
                              hipStream_t stream) {
    const float* A_values  = (const float*)d_in[0];
    const int*   A_indices = (const int*)d_in[1];   // int32 (JAX x64 disabled), [2, NNZ]
    const float* B         = (const float*)d_in[2];
    float*       out       = (float*)d_out;

    // workspace layout
    const size_t OFFSETS_OFF = 0;                               // 16385 u32
    const size_t COUNTS_OFF  = 66560;                           // 16384 u32 (becomes cursor)
    const size_t PAIRS_OFF   = COUNTS_OFF + 65536;              // 8 MB
    const size_t BH_OFF      = PAIRS_OFF + (size_t)NNZ_C * 8;   // 8 MB bf16 B
    const size_t NEED_FP32   = BH_OFF;                          // ~8.5 MB
    const size_t NEED_BF16   = BH_OFF + (size_t)M_ROWS * NCOL * 2;

    if (ws_size < NEED_FP32) {
        hipMemsetAsync(d_out, 0, (size_t)out_size * sizeof(float), stream);
        spmm_atomic_kernel<<<NNZ_C / 4, 256, 0, stream>>>(A_values, A_indices, B, out);
        return;
    }

    uint8_t* w = (uint8_t*)d_ws;
    unsigned int*   offsets = (unsigned int*)(w + OFFSETS_OFF);
    unsigned int*   counts  = (unsigned int*)(w + COUNTS_OFF);  // also cursor
    int2*           pairs   = (int2*)(w + PAIRS_OFF);
    unsigned short* Bh      = (unsigned short*)(w + BH_OFF);

    const bool use_bf16 = (ws_size >= NEED_BF16);

    if (use_bf16) {
        bconv_kernel<<<2048, 256, 0, stream>>>((const float4*)B, (uint4*)Bh);
    }
    hipMemsetAsync(counts, 0, M_ROWS * sizeof(unsigned int), stream);
    hist_sharded_kernel<<<CHUNKS * NSHARD, 256, 0, stream>>>(A_indices, counts);
    scan_kernel<<<1, 1024, 0, stream>>>(counts, offsets, counts /*cursor*/);
    scatter_sharded_kernel<<<CHUNKS * NSHARD, 256, 0, stream>>>(A_indices, A_values, counts, pairs);

    if (use_bf16) {
        spmm_bf16_kernel<<<M_ROWS / 4, 256, 0, stream>>>(offsets, pairs, Bh, out);
    } else {
        spmm_csr_kernel<<<M_ROWS / 4, 256, 0, stream>>>(offsets, pairs, B, out);
    }
}

// Round 10
// 204.127 us; speedup vs baseline: 1.6596x; 1.0297x over previous
//
#include <hip/hip_runtime.h>
#include <stdint.h>

// SpMM: COO sparse A (16384x16384, 1,048,576 nnz) @ dense B (16384x256) -> out (16384x256)
// CSR-build (XCD-sharded, R8 form) + col-QUARTERED bf16 SpMM with XCD-pinned B slices.
//
// Round-10: spmm data shows both fp32 (121us/1GB) and bf16 (~57us/0.5GB) run at
// ~9 TB/s = L2-miss mixed tier, because 8MB B > 4MB per-XCD L2. Fix: split out
// cols into 4 quarters (2MB bf16 B-slice each, L2-resident); blockIdx&7 XCD
// round-robin pins quarter = xcd>>1. Each nnz processed 4x (line count per nnz
// invariant at 8), but gathers now hit the XCD's L2 (~34TB/s). pairs read 4x
// via nt loads (HBM, ~5us) to avoid polluting the B-resident L2.
// hist/scatter: nt loads REVERTED (R9: no WRITE_SIZE change, +49MB HBM FETCH).

#define M_ROWS 16384
#define NNZ_C  1048576
#define NCOL   256
#define NSHARD 8
#define SHARD_ROWS 2048            // M_ROWS / NSHARD
#define CHUNKS 256                 // nnz chunks; CHUNK_NNZ = NNZ_C/CHUNKS = 4096

typedef int vint2 __attribute__((ext_vector_type(2)));

__device__ __forceinline__ float bf16_lo(unsigned int u) { return __uint_as_float(u << 16); }
__device__ __forceinline__ float bf16_hi(unsigned int u) { return __uint_as_float(u & 0xffff0000u); }

// ---------------- phase 0: B fp32 -> bf16 (RNE), 8 elems/thread ----------------
__global__ __launch_bounds__(256) void bconv_kernel(const float4* __restrict__ Bf,
                                                    uint4* __restrict__ Bh) {
    const int i = blockIdx.x * 256 + threadIdx.x;      // 524288 threads
    const float4 a = Bf[i * 2];
    const float4 b = Bf[i * 2 + 1];
    unsigned int w[8];
    const float src[8] = {a.x, a.y, a.z, a.w, b.x, b.y, b.z, b.w};
#pragma unroll
    for (int k = 0; k < 8; ++k) {
        unsigned int bits = __float_as_uint(src[k]);
        w[k] = (bits + 0x7fffu + ((bits >> 16) & 1u)) >> 16;   // RNE bf16
    }
    Bh[i] = make_uint4(w[0] | (w[1] << 16), w[2] | (w[3] << 16),
                       w[4] | (w[5] << 16), w[6] | (w[7] << 16));
}

// ---------------- phase 1: XCD-sharded histogram (R8 form, cached reads) ----------------
__global__ __launch_bounds__(256) void hist_sharded_kernel(const int* __restrict__ idx,
                                                           unsigned int* __restrict__ counts) {
    const int shard = blockIdx.x & (NSHARD - 1);
    const int chunk = blockIdx.x >> 3;
    const int rlo   = shard * SHARD_ROWS;
#pragma unroll
    for (int k = 0; k < 4; ++k) {
        const int i4 = chunk * 1024 + k * 256 + threadIdx.x;
        const int4 r4 = ((const int4*)idx)[i4];
        if ((unsigned)(r4.x - rlo) < SHARD_ROWS) atomicAdd(&counts[r4.x], 1u);
        if ((unsigned)(r4.y - rlo) < SHARD_ROWS) atomicAdd(&counts[r4.y], 1u);
        if ((unsigned)(r4.z - rlo) < SHARD_ROWS) atomicAdd(&counts[r4.z], 1u);
        if ((unsigned)(r4.w - rlo) < SHARD_ROWS) atomicAdd(&counts[r4.w], 1u);
    }
}

// ---------------- phase 2: exclusive scan (1 block, 1024 thr x 16 bins) ----------------
__global__ __launch_bounds__(1024) void scan_kernel(const unsigned int* __restrict__ counts,
                                                    unsigned int* __restrict__ offsets,
                                                    unsigned int* __restrict__ cursor) {
    __shared__ unsigned int lds[1024];
    const int t = threadIdx.x;
    const uint4* c4 = (const uint4*)counts;
    uint4 L[4];
#pragma unroll
    for (int k = 0; k < 4; ++k) L[k] = c4[t * 4 + k];
    unsigned int local[16];
#pragma unroll
    for (int k = 0; k < 4; ++k) {
        local[k * 4 + 0] = L[k].x;
        local[k * 4 + 1] = L[k].y;
        local[k * 4 + 2] = L[k].z;
        local[k * 4 + 3] = L[k].w;
    }
    unsigned int sum = 0;
#pragma unroll
    for (int i = 0; i < 16; ++i) sum += local[i];
    lds[t] = sum;
    __syncthreads();
    for (int off = 1; off < 1024; off <<= 1) {
        unsigned int v = (t >= off) ? lds[t - off] : 0u;
        __syncthreads();
        lds[t] += v;
        __syncthreads();
    }
    unsigned int base = lds[t] - sum;
#pragma unroll
    for (int i = 0; i < 16; ++i) {
        offsets[t * 16 + i] = base;
        cursor[t * 16 + i]  = base;
        base += local[i];
    }
    if (t == 1023) offsets[M_ROWS] = lds[1023];
}

// ---------------- phase 3: XCD-sharded scatter (R8 form, cached reads) ----------------
__global__ __launch_bounds__(256) void scatter_sharded_kernel(const int* __restrict__ idx,
                                                              const float* __restrict__ vals,
                                                              unsigned int* __restrict__ cursor,
                                                              int2* __restrict__ pairs) {
    const int shard = blockIdx.x & (NSHARD - 1);
    const int chunk = blockIdx.x >> 3;
    const int rlo   = shard * SHARD_ROWS;
#pragma unroll
    for (int k = 0; k < 4; ++k) {
        const int i4 = chunk * 1024 + k * 256 + threadIdx.x;
        const int4   r4 = ((const int4*)idx)[i4];
        const int4   c4 = ((const int4*)(idx + NNZ_C))[i4];
        const float4 v4 = ((const float4*)vals)[i4];
        unsigned int p;
        if ((unsigned)(r4.x - rlo) < SHARD_ROWS) {
            p = atomicAdd(&cursor[r4.x], 1u); pairs[p] = make_int2(c4.x, __float_as_int(v4.x));
        }
        if ((unsigned)(r4.y - rlo) < SHARD_ROWS) {
            p = atomicAdd(&cursor[r4.y], 1u); pairs[p] = make_int2(c4.y, __float_as_int(v4.y));
        }
        if ((unsigned)(r4.z - rlo) < SHARD_ROWS) {
            p = atomicAdd(&cursor[r4.z], 1u); pairs[p] = make_int2(c4.z, __float_as_int(v4.z));
        }
        if ((unsigned)(r4.w - rlo) < SHARD_ROWS) {
            p = atomicAdd(&cursor[r4.w], 1u); pairs[p] = make_int2(c4.w, __float_as_int(v4.w));
        }
    }
}

// ---------------- phase 4: col-quartered SpMM, bf16 B, XCD-pinned quarter ----------------
// grid 16384: xcd = bid&7 picks quarter h = xcd>>1 (2MB B-slice, L2-resident per XCD);
// rowblk = (xcd&1)*2048 + (bid>>3). Wave = row; 8-lane group g per nnz (8 nnz per
// 1KB wave-gather); lane covers 8 cols of its quarter; 3-step shfl_xor reduce.
__global__ __launch_bounds__(256) void spmm_bf16_q_kernel(const unsigned int* __restrict__ offsets,
                                                          const int2* __restrict__ pairs,
                                                          const unsigned short* __restrict__ Bh,
                                                          float* __restrict__ out) {
    const int bid    = blockIdx.x;
    const int xcd    = bid & 7;
    const int slot   = bid >> 3;                 // 0..2047
    const int h      = xcd >> 1;                 // col quarter 0..3
    const int rowblk = (xcd & 1) * 2048 + slot;  // 0..4095
    const int row    = rowblk * 4 + (threadIdx.x >> 6);
    const int lane   = threadIdx.x & 63;
    const int g      = lane >> 3;                // nnz sub-group 0..7
    const int sub    = lane & 7;                 // owns cols h*64 + sub*8 .. +8

    unsigned int beg = __builtin_amdgcn_readfirstlane(offsets[row]);
    unsigned int end = __builtin_amdgcn_readfirstlane(offsets[row + 1]);

    const uint4* __restrict__ B16 = (const uint4*)Bh;   // bf16 row = 512B = 32 uint4
    float acc[8] = {0.f, 0.f, 0.f, 0.f, 0.f, 0.f, 0.f, 0.f};

    for (unsigned int base_p = beg; base_p < end; base_p += 64) {
        const unsigned int p = base_p + lane;
        int pc = 0, pv = 0;
        if (p < end) {
            // nt: pairs is a 4x-replicated read-once stream; keep it out of the
            // L2 that holds this XCD's 2MB B-slice.
            const vint2 pr = __builtin_nontemporal_load(((const vint2*)pairs) + p);
            pc = pr.x;
            pv = pr.y;
        }
#pragma unroll
        for (int j = 0; j < 64; j += 8) {
            const int   c = __shfl(pc, j + g, 64);
            const float v = __int_as_float(__shfl(pv, j + g, 64));
            const uint4 b = B16[(size_t)c * 32 + h * 8 + sub];   // 16B/lane; 128B per nnz-quarter
            acc[0] += v * bf16_lo(b.x);
            acc[1] += v * bf16_hi(b.x);
            acc[2] += v * bf16_lo(b.y);
            acc[3] += v * bf16_hi(b.y);
            acc[4] += v * bf16_lo(b.z);
            acc[5] += v * bf16_hi(b.z);
            acc[6] += v * bf16_lo(b.w);
            acc[7] += v * bf16_hi(b.w);
        }
    }
    // combine the 8 nnz-groups: lanes with equal sub hold partials of the same cols
#pragma unroll
    for (int k = 0; k < 8; ++k) {
        acc[k] += __shfl_xor(acc[k], 8, 64);
        acc[k] += __shfl_xor(acc[k], 16, 64);
        acc[k] += __shfl_xor(acc[k], 32, 64);
    }
    if (g == 0) {                                // lanes 0..7 store 256B (full lines)
        float* o = out + (size_t)row * NCOL + h * 64 + sub * 8;
        *(float4*)(o)     = make_float4(acc[0], acc[1], acc[2], acc[3]);
        *(float4*)(o + 4) = make_float4(acc[4], acc[5], acc[6], acc[7]);
    }
}

// ---------------- fp32 spmm (fallback tier 1) ----------------
__global__ __launch_bounds__(256) void spmm_csr_kernel(const unsigned int* __restrict__ offsets,
                                                       const int2* __restrict__ pairs,
                                                       const float* __restrict__ B,
                                                       float* __restrict__ out) {
    const int row  = blockIdx.x * 4 + (threadIdx.x >> 6);
    const int lane = threadIdx.x & 63;
    unsigned int beg = __builtin_amdgcn_readfirstlane(offsets[row]);
    unsigned int end = __builtin_amdgcn_readfirstlane(offsets[row + 1]);
    const float4* __restrict__ B4 = (const float4*)B;
    float4 acc = make_float4(0.f, 0.f, 0.f, 0.f);
    for (unsigned int base_p = beg; base_p < end; base_p += 64) {
        const unsigned int p = base_p + lane;
        int pc = 0, pv = 0;
        if (p < end) { int2 pr = pairs[p]; pc = pr.x; pv = pr.y; }
#pragma unroll 8
        for (int j = 0; j < 64; ++j) {
            const int   c = __builtin_amdgcn_readlane(pc, j);
            const float v = __int_as_float(__builtin_amdgcn_readlane(pv, j));
            const float4 b = B4[(size_t)c * 64 + lane];
            acc.x += v * b.x; acc.y += v * b.y; acc.z += v * b.z; acc.w += v * b.w;
        }
    }
    ((float4*)out)[(size_t)row * 64 + lane] = acc;
}

// ---------------- atomic fallback (tier 2) ----------------
__global__ __launch_bounds__(256) void spmm_atomic_kernel(
    const float* __restrict__ vals, const int* __restrict__ idx,
    const float* __restrict__ B, float* __restrict__ out) {
    const int wave = (int)(blockIdx.x * 4 + (threadIdx.x >> 6));
    const int lane = (int)(threadIdx.x & 63);
    if (wave >= NNZ_C) return;
    const int r = idx[wave];
    const int c = idx[NNZ_C + wave];
    const float v = vals[wave];
    const float* brow = B + (size_t)c * NCOL;
    float* orow = out + (size_t)r * NCOL;
#pragma unroll
    for (int k = 0; k < 4; ++k) {
        const int col = lane + 64 * k;
        atomicAdd(&orow[col], v * brow[col]);
    }
}

extern "C" void kernel_launch(void* const* d_in, const int* in_sizes, int n_in,
                              void* d_out, int out_size, void* d_ws, size_t ws_size,
                              hipStream_t stream) {
    const float* A_values  = (const float*)d_in[0];
    const int*   A_indices = (const int*)d_in[1];   // int32 (JAX x64 disabled), [2, NNZ]
    const float* B         = (const float*)d_in[2];
    float*       out       = (float*)d_out;

    // workspace layout
    const size_t OFFSETS_OFF = 0;                               // 16385 u32
    const size_t COUNTS_OFF  = 66560;                           // 16384 u32 (becomes cursor)
    const size_t PAIRS_OFF   = COUNTS_OFF + 65536;              // 8 MB
    const size_t BH_OFF      = PAIRS_OFF + (size_t)NNZ_C * 8;   // 8 MB bf16 B
    const size_t NEED_FP32   = BH_OFF;                          // ~8.5 MB
    const size_t NEED_BF16   = BH_OFF + (size_t)M_ROWS * NCOL * 2;

    if (ws_size < NEED_FP32) {
        hipMemsetAsync(d_out, 0, (size_t)out_size * sizeof(float), stream);
        spmm_atomic_kernel<<<NNZ_C / 4, 256, 0, stream>>>(A_values, A_indices, B, out);
        return;
    }

    uint8_t* w = (uint8_t*)d_ws;
    unsigned int*   offsets = (unsigned int*)(w + OFFSETS_OFF);
    unsigned int*   counts  = (unsigned int*)(w + COUNTS_OFF);  // also cursor
    int2*           pairs   = (int2*)(w + PAIRS_OFF);
    unsigned short* Bh      = (unsigned short*)(w + BH_OFF);

    const bool use_bf16 = (ws_size >= NEED_BF16);

    if (use_bf16) {
        bconv_kernel<<<2048, 256, 0, stream>>>((const float4*)B, (uint4*)Bh);
    }
    hipMemsetAsync(counts, 0, M_ROWS * sizeof(unsigned int), stream);
    hist_sharded_kernel<<<CHUNKS * NSHARD, 256, 0, stream>>>(A_indices, counts);
    scan_kernel<<<1, 1024, 0, stream>>>(counts, offsets, counts /*cursor*/);
    scatter_sharded_kernel<<<CHUNKS * NSHARD, 256, 0, stream>>>(A_indices, A_values, counts, pairs);

    if (use_bf16) {
        spmm_bf16_q_kernel<<<16384, 256, 0, stream>>>(offsets, pairs, Bh, out);
    } else {
        spmm_csr_kernel<<<M_ROWS / 4, 256, 0, stream>>>(offsets, pairs, B, out);
    }
}